// Round 1
// baseline (664.783 us; speedup 1.0000x reference)
//
#include <hip/hip_runtime.h>

#define NTOKS 64
#define DIMS 256
#define NHEADS 8
#define HDIM 32
#define NWIN 49
#define NBLK 3136

typedef __bf16 bf16x8 __attribute__((ext_vector_type(8)));
typedef float f32x4 __attribute__((ext_vector_type(4)));

__device__ __forceinline__ unsigned short f2bf(float f) {
    union { float f; unsigned u; } c; c.f = f;
    unsigned u = c.u;
    u += 0x7fffu + ((u >> 16) & 1u);   // RNE
    return (unsigned short)(u >> 16);
}

// ---------------- prep kernel: DPB MLP + rpb expand + weight bf16 swizzle ----------------
template<int NOUT>
__device__ __forceinline__ void ln_relu_fc(const float* v, const float* g, const float* bb,
                                           const float* fw, const float* fb, float* o) {
    float m = 0.f;
#pragma unroll
    for (int j = 0; j < 16; ++j) m += v[j];
    m *= (1.f / 16.f);
    float var = 0.f;
#pragma unroll
    for (int j = 0; j < 16; ++j) { float d = v[j] - m; var += d * d; }
    var *= (1.f / 16.f);
    float inv = rsqrtf(var + 1e-5f);
    float t[16];
#pragma unroll
    for (int j = 0; j < 16; ++j) {
        float xx = (v[j] - m) * inv * g[j] + bb[j];
        t[j] = xx > 0.f ? xx : 0.f;
    }
#pragma unroll
    for (int i = 0; i < NOUT; ++i) {
        float ss = fb[i];
#pragma unroll
        for (int j = 0; j < 16; ++j) ss += fw[i * 16 + j] * t[j];
        o[i] = ss;
    }
}

__global__ void prep_kernel(
    const float* __restrict__ qkv_w, const float* __restrict__ qkv_b,
    const float* __restrict__ proj_w,
    const float* __restrict__ pos_proj_w, const float* __restrict__ pos_proj_b,
    const float* __restrict__ ln1_g, const float* __restrict__ ln1_b,
    const float* __restrict__ fc1_w, const float* __restrict__ fc1_b,
    const float* __restrict__ ln2_g, const float* __restrict__ ln2_b,
    const float* __restrict__ fc2_w, const float* __restrict__ fc2_b,
    const float* __restrict__ ln3_g, const float* __restrict__ ln3_b,
    const float* __restrict__ fc3_w, const float* __restrict__ fc3_b,
    const float* __restrict__ biases, const int* __restrict__ rel_idx,
    unsigned short* __restrict__ qkvw_bf, unsigned short* __restrict__ projw_bf,
    float* __restrict__ qkvb_s, float* __restrict__ rpb)
{
    const int tid = threadIdx.x;
    const int b = blockIdx.x;
    const float SC = 0.17677669529663687f;  // 32^-0.5

    if (b == 0) {
        __shared__ float p_sh[225 * 8];
        if (tid < 225) {
            float bx = biases[2 * tid], by = biases[2 * tid + 1];
            float v[16], u[16];
#pragma unroll
            for (int j = 0; j < 16; ++j)
                v[j] = pos_proj_w[2 * j] * bx + pos_proj_w[2 * j + 1] * by + pos_proj_b[j];
            ln_relu_fc<16>(v, ln1_g, ln1_b, fc1_w, fc1_b, u);
            ln_relu_fc<16>(u, ln2_g, ln2_b, fc2_w, fc2_b, v);
            ln_relu_fc<8>(v, ln3_g, ln3_b, fc3_w, fc3_b, u);
#pragma unroll
            for (int h = 0; h < 8; ++h) p_sh[tid * 8 + h] = u[h];
        }
        __syncthreads();
        for (int e = tid; e < 4096; e += 256) {
            int ri = rel_idx[e];
#pragma unroll
            for (int h = 0; h < 8; ++h) rpb[h * 4096 + e] = p_sh[ri * 8 + h];
        }
    } else {
        // Swizzled bf16 weights: dst e = ((tile*8 + kk)*64 + lane)*8 + j
        // src = (tile*16 + (lane&15))*256 + kk*32 + (lane>>4)*8 + j
        const int t0 = (b - 1) * 256 + tid, NTH = 63 * 256;
        for (int e = t0; e < 196608; e += NTH) {
            int j = e & 7, lane = (e >> 3) & 63, kk = (e >> 9) & 7, tile = e >> 12;
            int src = (tile * 16 + (lane & 15)) * 256 + kk * 32 + (lane >> 4) * 8 + j;
            float f = qkv_w[src];
            if (src < 65536) f *= SC;   // q rows pre-scaled
            qkvw_bf[e] = f2bf(f);
        }
        for (int e = t0; e < 65536; e += NTH) {
            int j = e & 7, lane = (e >> 3) & 63, kk = (e >> 9) & 7, tile = e >> 12;
            int src = (tile * 16 + (lane & 15)) * 256 + kk * 32 + (lane >> 4) * 8 + j;
            projw_bf[e] = f2bf(proj_w[src]);
        }
        if (b == 1) {
            for (int e = tid; e < 768; e += 256)
                qkvb_s[e] = qkv_b[e] * (e < 256 ? SC : 1.f);
        }
    }
}

// ---------------- main fused kernel: one block per window ----------------
// LDS regions (ushort element offsets):
#define XS_OFF 0          // x tile bf16 [64][264]               16896 elems
#define Q_OFF  16896      // q bf16 [64 tok][264]                16896
#define K_OFF  33792      // k bf16 [64 tok][264]                16896
#define VT_OFF 50688      // v^T bf16 [256 dim][72 tok]          18432
#define LDS_TOT 69120     // 138240 bytes
#define PS_OFF 0          // P bf16 [8 head][64][72] = 36864 elems, overlays xs+q+k-head (after barrier)
#define CTX_OFF 0         // ctx bf16 [64][264], overlays ps heads 0-3 (after barrier)

__global__ __launch_bounds__(512, 2) void attn_kernel(
    const float* __restrict__ x, const float* __restrict__ mask,
    const unsigned short* __restrict__ qkvw, const float* __restrict__ qkvb,
    const unsigned short* __restrict__ projw, const float* __restrict__ projb,
    const float* __restrict__ rpb, float* __restrict__ out)
{
    __shared__ __align__(16) unsigned short lds[LDS_TOT];
    const int tid  = threadIdx.x;
    const int wv   = tid >> 6;
    const int lane = tid & 63;
    const int quad = lane >> 4;
    const int l16  = lane & 15;
    const int blk  = blockIdx.x;
    const int w    = blk % NWIN;
    const f32x4 FZ = {0.f, 0.f, 0.f, 0.f};

    // ---- stage x -> xs (fp32 -> bf16) ----
    {
        const float4* xv = (const float4*)(x + (size_t)blk * (NTOKS * DIMS));
        for (int i = tid; i < NTOKS * DIMS / 4; i += 512) {
            float4 f = xv[i];
            int row = i >> 6, c4 = (i & 63) << 2;
            ushort4 u;
            u.x = f2bf(f.x); u.y = f2bf(f.y); u.z = f2bf(f.z); u.w = f2bf(f.w);
            *(ushort4*)&lds[XS_OFF + row * 264 + c4] = u;
        }
    }
    __syncthreads();

    // ---- phase A: QKV = xs @ Wqkv^T + b ; wave covers 96 output cols ----
    {
        f32x4 acc[4][6];
#pragma unroll
        for (int mt = 0; mt < 4; ++mt)
#pragma unroll
            for (int nt = 0; nt < 6; ++nt) acc[mt][nt] = FZ;
        const unsigned short* wq = qkvw + (size_t)(wv * 6) * 8 * 512;
        for (int kk = 0; kk < 8; ++kk) {
            bf16x8 a[4], bb[6];
#pragma unroll
            for (int mt = 0; mt < 4; ++mt)
                a[mt] = *(const bf16x8*)&lds[XS_OFF + (mt * 16 + l16) * 264 + kk * 32 + quad * 8];
#pragma unroll
            for (int nt = 0; nt < 6; ++nt)
                bb[nt] = *(const bf16x8*)&wq[(nt * 8 + kk) * 512 + lane * 8];
#pragma unroll
            for (int nt = 0; nt < 6; ++nt)
#pragma unroll
                for (int mt = 0; mt < 4; ++mt)
                    acc[mt][nt] = __builtin_amdgcn_mfma_f32_16x16x32_bf16(a[mt], bb[nt], acc[mt][nt], 0, 0, 0);
        }
#pragma unroll
        for (int nt = 0; nt < 6; ++nt) {
            int o = wv * 96 + nt * 16 + l16;
            float bias = qkvb[o];
            if (o < 256) {
#pragma unroll
                for (int mt = 0; mt < 4; ++mt)
#pragma unroll
                    for (int r = 0; r < 4; ++r)
                        lds[Q_OFF + (mt * 16 + quad * 4 + r) * 264 + o] = f2bf(acc[mt][nt][r] + bias);
            } else if (o < 512) {
                int oo = o - 256;
#pragma unroll
                for (int mt = 0; mt < 4; ++mt)
#pragma unroll
                    for (int r = 0; r < 4; ++r)
                        lds[K_OFF + (mt * 16 + quad * 4 + r) * 264 + oo] = f2bf(acc[mt][nt][r] + bias);
            } else {
                int oo = o - 512;   // v stored transposed: vT[dim][token]
#pragma unroll
                for (int mt = 0; mt < 4; ++mt) {
                    ushort4 u;
                    u.x = f2bf(acc[mt][nt][0] + bias);
                    u.y = f2bf(acc[mt][nt][1] + bias);
                    u.z = f2bf(acc[mt][nt][2] + bias);
                    u.w = f2bf(acc[mt][nt][3] + bias);
                    *(ushort4*)&lds[VT_OFF + oo * 72 + mt * 16 + quad * 4] = u;
                }
            }
        }
    }
    __syncthreads();

    // ---- phase B: per-wave head, S = q @ k^T (scale already folded into Wq) ----
    f32x4 s[4][4];
    {
        bf16x8 aq[4], bk[4];
#pragma unroll
        for (int mt = 0; mt < 4; ++mt)
            aq[mt] = *(const bf16x8*)&lds[Q_OFF + (mt * 16 + l16) * 264 + wv * 32 + quad * 8];
#pragma unroll
        for (int nt = 0; nt < 4; ++nt)
            bk[nt] = *(const bf16x8*)&lds[K_OFF + (nt * 16 + l16) * 264 + wv * 32 + quad * 8];
#pragma unroll
        for (int mt = 0; mt < 4; ++mt)
#pragma unroll
            for (int nt = 0; nt < 4; ++nt)
                s[mt][nt] = __builtin_amdgcn_mfma_f32_16x16x32_bf16(aq[mt], bk[nt], FZ, 0, 0, 0);
    }
    {
        const float* rp = rpb + wv * 4096;
        const float* mk = mask + w * 4096;
#pragma unroll
        for (int mt = 0; mt < 4; ++mt)
#pragma unroll
            for (int r = 0; r < 4; ++r) {
                int m = mt * 16 + quad * 4 + r;
#pragma unroll
                for (int nt = 0; nt < 4; ++nt) {
                    int n = nt * 16 + l16;
                    s[mt][nt][r] += rp[m * 64 + n] + mk[m * 64 + n];
                }
            }
    }
    // softmax over keys: within-lane over nt, then across the 16 lanes of the quad
#pragma unroll
    for (int mt = 0; mt < 4; ++mt)
#pragma unroll
        for (int r = 0; r < 4; ++r) {
            float mx = fmaxf(fmaxf(s[mt][0][r], s[mt][1][r]), fmaxf(s[mt][2][r], s[mt][3][r]));
            mx = fmaxf(mx, __shfl_xor(mx, 1));
            mx = fmaxf(mx, __shfl_xor(mx, 2));
            mx = fmaxf(mx, __shfl_xor(mx, 4));
            mx = fmaxf(mx, __shfl_xor(mx, 8));
            float sum = 0.f;
#pragma unroll
            for (int nt = 0; nt < 4; ++nt) {
                float e = __expf(s[mt][nt][r] - mx);
                s[mt][nt][r] = e; sum += e;
            }
            sum += __shfl_xor(sum, 1);
            sum += __shfl_xor(sum, 2);
            sum += __shfl_xor(sum, 4);
            sum += __shfl_xor(sum, 8);
            float inv = 1.0f / sum;
#pragma unroll
            for (int nt = 0; nt < 4; ++nt) s[mt][nt][r] *= inv;
        }
    __syncthreads();   // all q/k reads complete before ps overlays them

    // write P to LDS (C-layout -> A-layout round trip)
#pragma unroll
    for (int mt = 0; mt < 4; ++mt)
#pragma unroll
        for (int r = 0; r < 4; ++r) {
            int m = mt * 16 + quad * 4 + r;
#pragma unroll
            for (int nt = 0; nt < 4; ++nt)
                lds[PS_OFF + wv * 4608 + m * 72 + nt * 16 + l16] = f2bf(s[mt][nt][r]);
        }
    __syncthreads();

    // PV: O = P @ V  (B-frags from vT, contiguous)
    f32x4 ov[4][2];
#pragma unroll
    for (int mt = 0; mt < 4; ++mt)
#pragma unroll
        for (int nt = 0; nt < 2; ++nt) ov[mt][nt] = FZ;
#pragma unroll
    for (int ks = 0; ks < 2; ++ks) {
        bf16x8 ap[4], bv[2];
#pragma unroll
        for (int mt = 0; mt < 4; ++mt)
            ap[mt] = *(const bf16x8*)&lds[PS_OFF + wv * 4608 + (mt * 16 + l16) * 72 + ks * 32 + quad * 8];
#pragma unroll
        for (int nt = 0; nt < 2; ++nt)
            bv[nt] = *(const bf16x8*)&lds[VT_OFF + (wv * 32 + nt * 16 + l16) * 72 + ks * 32 + quad * 8];
#pragma unroll
        for (int mt = 0; mt < 4; ++mt)
#pragma unroll
            for (int nt = 0; nt < 2; ++nt)
                ov[mt][nt] = __builtin_amdgcn_mfma_f32_16x16x32_bf16(ap[mt], bv[nt], ov[mt][nt], 0, 0, 0);
    }
    __syncthreads();   // all ps reads done before ctx overlays

    // ctx[t][h*32+d] bf16
#pragma unroll
    for (int mt = 0; mt < 4; ++mt)
#pragma unroll
        for (int r = 0; r < 4; ++r) {
            int t = mt * 16 + quad * 4 + r;
#pragma unroll
            for (int nt = 0; nt < 2; ++nt)
                lds[CTX_OFF + t * 264 + wv * 32 + nt * 16 + l16] = f2bf(ov[mt][nt][r]);
        }
    __syncthreads();

    // ---- phase C: out = ctx @ Wproj^T + b ; wave covers 32 output cols ----
    {
        f32x4 accC[4][2];
#pragma unroll
        for (int mt = 0; mt < 4; ++mt)
#pragma unroll
            for (int nt = 0; nt < 2; ++nt) accC[mt][nt] = FZ;
        const unsigned short* pw = projw + (size_t)(wv * 2) * 8 * 512;
        for (int kk = 0; kk < 8; ++kk) {
            bf16x8 a[4], bb[2];
#pragma unroll
            for (int mt = 0; mt < 4; ++mt)
                a[mt] = *(const bf16x8*)&lds[CTX_OFF + (mt * 16 + l16) * 264 + kk * 32 + quad * 8];
#pragma unroll
            for (int nt = 0; nt < 2; ++nt)
                bb[nt] = *(const bf16x8*)&pw[(nt * 8 + kk) * 512 + lane * 8];
#pragma unroll
            for (int nt = 0; nt < 2; ++nt)
#pragma unroll
                for (int mt = 0; mt < 4; ++mt)
                    accC[mt][nt] = __builtin_amdgcn_mfma_f32_16x16x32_bf16(a[mt], bb[nt], accC[mt][nt], 0, 0, 0);
        }
        float* ob = out + (size_t)blk * (NTOKS * DIMS);
#pragma unroll
        for (int nt = 0; nt < 2; ++nt) {
            int o = wv * 32 + nt * 16 + l16;
            float pb = projb[o];
#pragma unroll
            for (int mt = 0; mt < 4; ++mt)
#pragma unroll
                for (int r = 0; r < 4; ++r)
                    ob[(mt * 16 + quad * 4 + r) * 256 + o] = accC[mt][nt][r] + pb;
        }
    }
}

extern "C" void kernel_launch(void* const* d_in, const int* in_sizes, int n_in,
                              void* d_out, int out_size, void* d_ws, size_t ws_size,
                              hipStream_t stream) {
    const float* x          = (const float*)d_in[0];
    const float* mask       = (const float*)d_in[1];
    const float* qkv_w      = (const float*)d_in[2];
    const float* qkv_b      = (const float*)d_in[3];
    const float* proj_w     = (const float*)d_in[4];
    const float* proj_b     = (const float*)d_in[5];
    const float* pos_proj_w = (const float*)d_in[6];
    const float* pos_proj_b = (const float*)d_in[7];
    const float* ln1_g      = (const float*)d_in[8];
    const float* ln1_b      = (const float*)d_in[9];
    const float* fc1_w      = (const float*)d_in[10];
    const float* fc1_b      = (const float*)d_in[11];
    const float* ln2_g      = (const float*)d_in[12];
    const float* ln2_b      = (const float*)d_in[13];
    const float* fc2_w      = (const float*)d_in[14];
    const float* fc2_b      = (const float*)d_in[15];
    const float* ln3_g      = (const float*)d_in[16];
    const float* ln3_b      = (const float*)d_in[17];
    const float* fc3_w      = (const float*)d_in[18];
    const float* fc3_b      = (const float*)d_in[19];
    const float* biases     = (const float*)d_in[20];
    const int*   rel_idx    = (const int*)d_in[21];
    float* out = (float*)d_out;

    char* ws = (char*)d_ws;
    unsigned short* qkvw_bf = (unsigned short*)(ws);            // 393216 B
    unsigned short* projw_bf = (unsigned short*)(ws + 393216);  // 131072 B
    float* qkvb_s = (float*)(ws + 524288);                      // 3072 B
    float* rpb    = (float*)(ws + 528384);                      // 131072 B -> end 659456

    prep_kernel<<<dim3(64), dim3(256), 0, stream>>>(
        qkv_w, qkv_b, proj_w, pos_proj_w, pos_proj_b,
        ln1_g, ln1_b, fc1_w, fc1_b, ln2_g, ln2_b, fc2_w, fc2_b,
        ln3_g, ln3_b, fc3_w, fc3_b, biases, rel_idx,
        qkvw_bf, projw_bf, qkvb_s, rpb);

    attn_kernel<<<dim3(NBLK), dim3(512), 0, stream>>>(
        x, mask, qkvw_bf, qkvb_s, projw_bf, proj_b, rpb, out);
}

// Round 2
// 609.795 us; speedup vs baseline: 1.0902x; 1.0902x over previous
//
#include <hip/hip_runtime.h>

#define NTOKS 64
#define DIMS 256
#define NHEADS 8
#define HDIM 32
#define NWIN 49
#define NBLK 3136

typedef __bf16 bf16x8 __attribute__((ext_vector_type(8)));
typedef float f32x4 __attribute__((ext_vector_type(4)));

__device__ __forceinline__ unsigned short f2bf(float f) {
    union { float f; unsigned u; } c; c.f = f;
    unsigned u = c.u;
    u += 0x7fffu + ((u >> 16) & 1u);   // RNE
    return (unsigned short)(u >> 16);
}

// ---------------- prep kernel ----------------
template<int NOUT>
__device__ __forceinline__ void ln_relu_fc(const float* v, const float* g, const float* bb,
                                           const float* fw, const float* fb, float* o) {
    float m = 0.f;
#pragma unroll
    for (int j = 0; j < 16; ++j) m += v[j];
    m *= (1.f / 16.f);
    float var = 0.f;
#pragma unroll
    for (int j = 0; j < 16; ++j) { float d = v[j] - m; var += d * d; }
    var *= (1.f / 16.f);
    float inv = rsqrtf(var + 1e-5f);
    float t[16];
#pragma unroll
    for (int j = 0; j < 16; ++j) {
        float xx = (v[j] - m) * inv * g[j] + bb[j];
        t[j] = xx > 0.f ? xx : 0.f;
    }
#pragma unroll
    for (int i = 0; i < NOUT; ++i) {
        float ss = fb[i];
#pragma unroll
        for (int j = 0; j < 16; ++j) ss += fw[i * 16 + j] * t[j];
        o[i] = ss;
    }
}

__global__ void prep_kernel(
    const float* __restrict__ qkv_w, const float* __restrict__ qkv_b,
    const float* __restrict__ proj_w, const float* __restrict__ mask,
    const float* __restrict__ pos_proj_w, const float* __restrict__ pos_proj_b,
    const float* __restrict__ ln1_g, const float* __restrict__ ln1_b,
    const float* __restrict__ fc1_w, const float* __restrict__ fc1_b,
    const float* __restrict__ ln2_g, const float* __restrict__ ln2_b,
    const float* __restrict__ fc2_w, const float* __restrict__ fc2_b,
    const float* __restrict__ ln3_g, const float* __restrict__ ln3_b,
    const float* __restrict__ fc3_w, const float* __restrict__ fc3_b,
    const float* __restrict__ biases, const int* __restrict__ rel_idx,
    unsigned short* __restrict__ qkvw_bf, unsigned short* __restrict__ projw_bf,
    float* __restrict__ qkvb_s, float* __restrict__ rpb_perm,
    float* __restrict__ mask_perm)
{
    const int tid = threadIdx.x;
    const int b = blockIdx.x;
    const float SC = 0.17677669529663687f;  // 32^-0.5

    if (b == 0) {
        __shared__ float p_sh[225 * 8];
        if (tid < 225) {
            float bx = biases[2 * tid], by = biases[2 * tid + 1];
            float v[16], u[16];
#pragma unroll
            for (int j = 0; j < 16; ++j)
                v[j] = pos_proj_w[2 * j] * bx + pos_proj_w[2 * j + 1] * by + pos_proj_b[j];
            ln_relu_fc<16>(v, ln1_g, ln1_b, fc1_w, fc1_b, u);
            ln_relu_fc<16>(u, ln2_g, ln2_b, fc2_w, fc2_b, v);
            ln_relu_fc<8>(v, ln3_g, ln3_b, fc3_w, fc3_b, u);
#pragma unroll
            for (int h = 0; h < 8; ++h) p_sh[tid * 8 + h] = u[h];
        }
        __syncthreads();
        // rpb_perm[h][m][l16][nt] = p(rel_idx[m][nt*16+l16], h)
        for (int e = tid; e < 32768; e += 256) {
            int nt = e & 3, l16 = (e >> 2) & 15, m = (e >> 6) & 63, h = e >> 12;
            rpb_perm[e] = p_sh[rel_idx[m * 64 + nt * 16 + l16] * 8 + h];
        }
    } else {
        const int t0 = (b - 1) * 256 + tid, NTH = 127 * 256;
        // bf16 swizzled weights: dst e = ((tile*8+kk)*64+lane)*8+j
        for (int e = t0; e < 196608; e += NTH) {
            int j = e & 7, lane = (e >> 3) & 63, kk = (e >> 9) & 7, tile = e >> 12;
            int src = (tile * 16 + (lane & 15)) * 256 + kk * 32 + (lane >> 4) * 8 + j;
            float f = qkv_w[src];
            if (src < 65536) f *= SC;   // q rows pre-scaled
            qkvw_bf[e] = f2bf(f);
        }
        for (int e = t0; e < 65536; e += NTH) {
            int j = e & 7, lane = (e >> 3) & 63, kk = (e >> 9) & 7, tile = e >> 12;
            int src = (tile * 16 + (lane & 15)) * 256 + kk * 32 + (lane >> 4) * 8 + j;
            projw_bf[e] = f2bf(proj_w[src]);
        }
        // mask_perm[w][m][l16][nt] = mask[w][m][nt*16+l16]
        for (int e = t0; e < 200704; e += NTH) {
            int nt = e & 3, l16 = (e >> 2) & 15, m = (e >> 6) & 63, w = e >> 12;
            mask_perm[e] = mask[w * 4096 + m * 64 + nt * 16 + l16];
        }
        if (b == 1) {
            for (int e = tid; e < 768; e += 256)
                qkvb_s[e] = qkv_b[e] * (e < 256 ? SC : 1.f);
        }
    }
}

// ---------------- main fused kernel: one block (1024 thr / 16 waves) per window ----------------
#define XS_OFF 0          // x bf16 [64][264]          16896 elems
#define Q_OFF  16896      // q bf16 [64][264]          16896
#define K_OFF  33792      // k bf16 [64][264]          16896
#define VT_OFF 50688      // v^T bf16 [256][72]        18432
#define LDS_TOT 69120     // 138240 B
#define PS_OFF 0          // P bf16 [8][64][72] = 36864 elems (overlays xs/q/k after barrier)
#define CTX_OFF 0         // ctx bf16 [64][264] (overlays ps heads 0-3 after barrier)
#define FO_OFF 16896      // out fp32 [64][260] at float*(&lds[16896]) (66560 B, no overlap w/ ctx)

__global__ __launch_bounds__(1024, 4) void attn_kernel(
    const float* __restrict__ x,
    const unsigned short* __restrict__ qkvw, const float* __restrict__ qkvb,
    const unsigned short* __restrict__ projw, const float* __restrict__ projb,
    const float* __restrict__ rpb_perm, const float* __restrict__ mask_perm,
    float* __restrict__ out)
{
    __shared__ __align__(16) unsigned short lds[LDS_TOT];
    const int tid  = threadIdx.x;
    const int wv   = tid >> 6;          // 0..15
    const int lane = tid & 63;
    const int quad = lane >> 4;
    const int l16  = lane & 15;
    const int blk  = blockIdx.x;
    const int w    = blk % NWIN;
    const f32x4 FZ = {0.f, 0.f, 0.f, 0.f};

    // ---- stage x -> xs (fp32 -> bf16) ----
    {
        const float4* xv = (const float4*)(x + (size_t)blk * (NTOKS * DIMS));
        for (int i = tid; i < NTOKS * DIMS / 4; i += 1024) {
            float4 f = xv[i];
            int row = i >> 6, c4 = (i & 63) << 2;
            ushort4 u;
            u.x = f2bf(f.x); u.y = f2bf(f.y); u.z = f2bf(f.z); u.w = f2bf(f.w);
            *(ushort4*)&lds[XS_OFF + row * 264 + c4] = u;
        }
    }
    __syncthreads();

    // ---- phase A: QKV = xs @ Wqkv^T + b ; wave covers 48 output cols ----
    {
        f32x4 acc[4][3];
#pragma unroll
        for (int mt = 0; mt < 4; ++mt)
#pragma unroll
            for (int nt = 0; nt < 3; ++nt) acc[mt][nt] = FZ;
        const unsigned short* wq = qkvw + (size_t)(wv * 3) * 8 * 512;
        for (int kk = 0; kk < 8; ++kk) {
            bf16x8 a[4], bb[3];
#pragma unroll
            for (int mt = 0; mt < 4; ++mt)
                a[mt] = *(const bf16x8*)&lds[XS_OFF + (mt * 16 + l16) * 264 + kk * 32 + quad * 8];
#pragma unroll
            for (int nt = 0; nt < 3; ++nt)
                bb[nt] = *(const bf16x8*)&wq[(nt * 8 + kk) * 512 + lane * 8];
#pragma unroll
            for (int nt = 0; nt < 3; ++nt)
#pragma unroll
                for (int mt = 0; mt < 4; ++mt)
                    acc[mt][nt] = __builtin_amdgcn_mfma_f32_16x16x32_bf16(a[mt], bb[nt], acc[mt][nt], 0, 0, 0);
        }
#pragma unroll
        for (int nt = 0; nt < 3; ++nt) {
            int ob = wv * 48 + nt * 16;       // wave-uniform region select
            int o = ob + l16;
            float bias = qkvb[o];
            if (ob < 256) {
#pragma unroll
                for (int mt = 0; mt < 4; ++mt)
#pragma unroll
                    for (int r = 0; r < 4; ++r)
                        lds[Q_OFF + (mt * 16 + quad * 4 + r) * 264 + o] = f2bf(acc[mt][nt][r] + bias);
            } else if (ob < 512) {
                int oo = o - 256;
#pragma unroll
                for (int mt = 0; mt < 4; ++mt)
#pragma unroll
                    for (int r = 0; r < 4; ++r)
                        lds[K_OFF + (mt * 16 + quad * 4 + r) * 264 + oo] = f2bf(acc[mt][nt][r] + bias);
            } else {
                int oo = o - 512;   // vT[dim][token]
#pragma unroll
                for (int mt = 0; mt < 4; ++mt) {
                    ushort4 u;
                    u.x = f2bf(acc[mt][nt][0] + bias);
                    u.y = f2bf(acc[mt][nt][1] + bias);
                    u.z = f2bf(acc[mt][nt][2] + bias);
                    u.w = f2bf(acc[mt][nt][3] + bias);
                    *(ushort4*)&lds[VT_OFF + oo * 72 + mt * 16 + quad * 4] = u;
                }
            }
        }
    }
    __syncthreads();

    // ---- phase B: 2 waves per head; wave handles 32 query rows ----
    const int h  = wv >> 1;
    const int hf = wv & 1;
    f32x4 s[2][4];
    {
        bf16x8 aq[2], bk[4];
#pragma unroll
        for (int mt = 0; mt < 2; ++mt)
            aq[mt] = *(const bf16x8*)&lds[Q_OFF + (hf * 32 + mt * 16 + l16) * 264 + h * 32 + quad * 8];
#pragma unroll
        for (int nt = 0; nt < 4; ++nt)
            bk[nt] = *(const bf16x8*)&lds[K_OFF + (nt * 16 + l16) * 264 + h * 32 + quad * 8];
#pragma unroll
        for (int mt = 0; mt < 2; ++mt)
#pragma unroll
            for (int nt = 0; nt < 4; ++nt)
                s[mt][nt] = __builtin_amdgcn_mfma_f32_16x16x32_bf16(aq[mt], bk[nt], FZ, 0, 0, 0);
    }
    {
        const f32x4* rp4 = (const f32x4*)rpb_perm;
        const f32x4* mk4 = (const f32x4*)mask_perm;
#pragma unroll
        for (int mt = 0; mt < 2; ++mt)
#pragma unroll
            for (int r = 0; r < 4; ++r) {
                int m = hf * 32 + mt * 16 + quad * 4 + r;
                f32x4 rv = rp4[(h * 64 + m) * 16 + l16];
                f32x4 mv = mk4[(w * 64 + m) * 16 + l16];
#pragma unroll
                for (int nt = 0; nt < 4; ++nt)
                    s[mt][nt][r] += rv[nt] + mv[nt];
            }
    }
    // softmax over keys (within-lane over nt, then across 16 lanes of the quad)
#pragma unroll
    for (int mt = 0; mt < 2; ++mt)
#pragma unroll
        for (int r = 0; r < 4; ++r) {
            float mx = fmaxf(fmaxf(s[mt][0][r], s[mt][1][r]), fmaxf(s[mt][2][r], s[mt][3][r]));
            mx = fmaxf(mx, __shfl_xor(mx, 1));
            mx = fmaxf(mx, __shfl_xor(mx, 2));
            mx = fmaxf(mx, __shfl_xor(mx, 4));
            mx = fmaxf(mx, __shfl_xor(mx, 8));
            float sum = 0.f;
#pragma unroll
            for (int nt = 0; nt < 4; ++nt) {
                float e = __expf(s[mt][nt][r] - mx);
                s[mt][nt][r] = e; sum += e;
            }
            sum += __shfl_xor(sum, 1);
            sum += __shfl_xor(sum, 2);
            sum += __shfl_xor(sum, 4);
            sum += __shfl_xor(sum, 8);
            float inv = 1.0f / sum;
#pragma unroll
            for (int nt = 0; nt < 4; ++nt) s[mt][nt][r] *= inv;
        }
    __syncthreads();   // all q/k reads complete before ps overlays them

    // write P (C-layout -> A-layout round trip)
#pragma unroll
    for (int mt = 0; mt < 2; ++mt)
#pragma unroll
        for (int r = 0; r < 4; ++r) {
            int m = hf * 32 + mt * 16 + quad * 4 + r;
#pragma unroll
            for (int nt = 0; nt < 4; ++nt)
                lds[PS_OFF + h * 4608 + m * 72 + nt * 16 + l16] = f2bf(s[mt][nt][r]);
        }
    __syncthreads();

    // PV: O = P @ V
    f32x4 ov[2][2];
#pragma unroll
    for (int mt = 0; mt < 2; ++mt)
#pragma unroll
        for (int nt = 0; nt < 2; ++nt) ov[mt][nt] = FZ;
#pragma unroll
    for (int ks = 0; ks < 2; ++ks) {
        bf16x8 ap[2], bv[2];
#pragma unroll
        for (int mt = 0; mt < 2; ++mt)
            ap[mt] = *(const bf16x8*)&lds[PS_OFF + h * 4608 + (hf * 32 + mt * 16 + l16) * 72 + ks * 32 + quad * 8];
#pragma unroll
        for (int nt = 0; nt < 2; ++nt)
            bv[nt] = *(const bf16x8*)&lds[VT_OFF + (h * 32 + nt * 16 + l16) * 72 + ks * 32 + quad * 8];
#pragma unroll
        for (int mt = 0; mt < 2; ++mt)
#pragma unroll
            for (int nt = 0; nt < 2; ++nt)
                ov[mt][nt] = __builtin_amdgcn_mfma_f32_16x16x32_bf16(ap[mt], bv[nt], ov[mt][nt], 0, 0, 0);
    }
    __syncthreads();   // all ps reads done before ctx overlays

    // ctx[t][h*32+d] bf16
#pragma unroll
    for (int mt = 0; mt < 2; ++mt)
#pragma unroll
        for (int r = 0; r < 4; ++r) {
            int t = hf * 32 + mt * 16 + quad * 4 + r;
#pragma unroll
            for (int nt = 0; nt < 2; ++nt)
                lds[CTX_OFF + t * 264 + h * 32 + nt * 16 + l16] = f2bf(ov[mt][nt][r]);
        }
    __syncthreads();

    // ---- phase C: out = ctx @ Wproj^T + b ; wave covers 16 output cols ----
    {
        f32x4 accC[4];
#pragma unroll
        for (int mt = 0; mt < 4; ++mt) accC[mt] = FZ;
        const unsigned short* pw = projw + (size_t)wv * 8 * 512;
        for (int kk = 0; kk < 8; ++kk) {
            bf16x8 a[4];
#pragma unroll
            for (int mt = 0; mt < 4; ++mt)
                a[mt] = *(const bf16x8*)&lds[CTX_OFF + (mt * 16 + l16) * 264 + kk * 32 + quad * 8];
            bf16x8 bb = *(const bf16x8*)&pw[kk * 512 + lane * 8];
#pragma unroll
            for (int mt = 0; mt < 4; ++mt)
                accC[mt] = __builtin_amdgcn_mfma_f32_16x16x32_bf16(a[mt], bb, accC[mt], 0, 0, 0);
        }
        // stage result fp32 in LDS (stride 260), then coalesced float4 store
        float* fo = (float*)&lds[FO_OFF];
        int o = wv * 16 + l16;
        float pb = projb[o];
#pragma unroll
        for (int mt = 0; mt < 4; ++mt)
#pragma unroll
            for (int r = 0; r < 4; ++r)
                fo[(mt * 16 + quad * 4 + r) * 260 + o] = accC[mt][r] + pb;
    }
    __syncthreads();
    {
        float* ob = out + (size_t)blk * (NTOKS * DIMS);
        const float* fo = (const float*)&lds[FO_OFF];
        for (int i = tid; i < NTOKS * DIMS / 4; i += 1024) {
            int row = i >> 6, c4 = (i & 63) << 2;
            float4 v = *(const float4*)&fo[row * 260 + c4];
            *(float4*)&ob[row * 256 + c4] = v;
        }
    }
}

extern "C" void kernel_launch(void* const* d_in, const int* in_sizes, int n_in,
                              void* d_out, int out_size, void* d_ws, size_t ws_size,
                              hipStream_t stream) {
    const float* x          = (const float*)d_in[0];
    const float* mask       = (const float*)d_in[1];
    const float* qkv_w      = (const float*)d_in[2];
    const float* qkv_b      = (const float*)d_in[3];
    const float* proj_w     = (const float*)d_in[4];
    const float* proj_b     = (const float*)d_in[5];
    const float* pos_proj_w = (const float*)d_in[6];
    const float* pos_proj_b = (const float*)d_in[7];
    const float* ln1_g      = (const float*)d_in[8];
    const float* ln1_b      = (const float*)d_in[9];
    const float* fc1_w      = (const float*)d_in[10];
    const float* fc1_b      = (const float*)d_in[11];
    const float* ln2_g      = (const float*)d_in[12];
    const float* ln2_b      = (const float*)d_in[13];
    const float* fc2_w      = (const float*)d_in[14];
    const float* fc2_b      = (const float*)d_in[15];
    const float* ln3_g      = (const float*)d_in[16];
    const float* ln3_b      = (const float*)d_in[17];
    const float* fc3_w      = (const float*)d_in[18];
    const float* fc3_b      = (const float*)d_in[19];
    const float* biases     = (const float*)d_in[20];
    const int*   rel_idx    = (const int*)d_in[21];
    float* out = (float*)d_out;

    char* ws = (char*)d_ws;
    unsigned short* qkvw_bf  = (unsigned short*)(ws);            // 393216 B
    unsigned short* projw_bf = (unsigned short*)(ws + 393216);   // 131072 B
    float* qkvb_s    = (float*)(ws + 524288);                    //   3072 B
    float* rpb_perm  = (float*)(ws + 528384);                    // 131072 B
    float* mask_perm = (float*)(ws + 659456);                    // 802816 B -> end 1462272

    prep_kernel<<<dim3(128), dim3(256), 0, stream>>>(
        qkv_w, qkv_b, proj_w, mask, pos_proj_w, pos_proj_b,
        ln1_g, ln1_b, fc1_w, fc1_b, ln2_g, ln2_b, fc2_w, fc2_b,
        ln3_g, ln3_b, fc3_w, fc3_b, biases, rel_idx,
        qkvw_bf, projw_bf, qkvb_s, rpb_perm, mask_perm);

    attn_kernel<<<dim3(NBLK), dim3(1024), 0, stream>>>(
        x, qkvw_bf, qkvb_s, projw_bf, proj_b, rpb_perm, mask_perm, out);
}